// Round 10
// baseline (208.259 us; speedup 1.0000x reference)
//
#include <hip/hip_runtime.h>
#include <hip/hip_bf16.h>

#define LRELU(val) ((val) >= 0.0f ? (val) : 0.01f * (val))

__device__ __forceinline__ float dot4(float4 a, float4 b, float acc) {
    return fmaf(a.x, b.x, fmaf(a.y, b.y, fmaf(a.z, b.z, fmaf(a.w, b.w, acc))));
}

// acc += quad `a` dotted with rows (4q..4q+3), column c, of a 32-col row-major slab
__device__ __forceinline__ float wdot4(const float* __restrict__ wbase, int c, int q,
                                       float4 a, float acc) {
    acc = fmaf(a.x, wbase[(4 * q + 0) * 32 + c], acc);
    acc = fmaf(a.y, wbase[(4 * q + 1) * 32 + c], acc);
    acc = fmaf(a.z, wbase[(4 * q + 2) * 32 + c], acc);
    acc = fmaf(a.w, wbase[(4 * q + 3) * 32 + c], acc);
    return acc;
}

__device__ inline int lower_bound_i(const int* __restrict__ a, int n, int v) {
    int lo = 0, hi = n;
    while (lo < hi) {
        int m = (lo + hi) >> 1;
        if (a[m] < v) lo = m + 1; else hi = m;
    }
    return lo;
}

// Coalesced tile-row load: float4 #p of a 32-row tile starting at candidate
// base_o. Consecutive lanes -> consecutive 16B (16 lines per instr, not 64).
__device__ __forceinline__ float4 tile_row_ld(const float* __restrict__ srcf,
                                              int start, int len, int Ns,
                                              int base_o, int p) {
    const int r = p >> 3, qd = p & 7;
    const int o = base_o + r;
    const int row = (o < len) ? (start + o) : min(start, Ns - 1);
    return reinterpret_cast<const float4*>(srcf)[(size_t)row * 8 + qd];
}

// Store float4 #p into the stride-33 padded tile (4 scalar writes; the
// (r + 4*qd) bank pattern is 2 lanes/bank = conflict-free).
__device__ __forceinline__ void st_tile(float* __restrict__ sT, int p, float4 v) {
    const int r = p >> 3, qd = p & 7;
    float* q = sT + r * 33 + qd * 4;
    q[0] = v.x; q[1] = v.y; q[2] = v.z; q[3] = v.w;
}

// One 32-row tile: coalesced global stage -> padded LDS -> half-dot per lane
// (row = lane&31, d-half = lane>>5, combine via shfl_xor 32). Owner half of
// tile TAU is (TAU&1) so candidate idx = start + lane + 64*(TAU>>1) — exactly
// the mapping the ballot selection below assumes.
#define DO_TILE(TAU, KREG) \
    if (len > (32 * (TAU))) { \
        float4 g0 = tile_row_ld(srcf, start, len, Ns, 32 * (TAU), lane); \
        float4 g1 = tile_row_ld(srcf, start, len, Ns, 32 * (TAU), lane + 64); \
        float4 g2 = tile_row_ld(srcf, start, len, Ns, 32 * (TAU), lane + 128); \
        float4 g3 = tile_row_ld(srcf, start, len, Ns, 32 * (TAU), lane + 192); \
        st_tile(sTileW, lane, g0);       st_tile(sTileW, lane + 64, g1); \
        st_tile(sTileW, lane + 128, g2); st_tile(sTileW, lane + 192, g3); \
        __builtin_amdgcn_wave_barrier(); \
        const float* tp = sTileW + (lane & 31) * 33 + h16; \
        float part = 0.0f; \
        part = fmaf(tp[0],  xh0.x, part); part = fmaf(tp[1],  xh0.y, part); \
        part = fmaf(tp[2],  xh0.z, part); part = fmaf(tp[3],  xh0.w, part); \
        part = fmaf(tp[4],  xh1.x, part); part = fmaf(tp[5],  xh1.y, part); \
        part = fmaf(tp[6],  xh1.z, part); part = fmaf(tp[7],  xh1.w, part); \
        part = fmaf(tp[8],  xh2.x, part); part = fmaf(tp[9],  xh2.y, part); \
        part = fmaf(tp[10], xh2.z, part); part = fmaf(tp[11], xh2.w, part); \
        part = fmaf(tp[12], xh3.x, part); part = fmaf(tp[13], xh3.y, part); \
        part = fmaf(tp[14], xh3.z, part); part = fmaf(tp[15], xh3.w, part); \
        const float dotf = part + __shfl_xor(part, 32); \
        const int o = 64 * ((TAU) >> 1) + lane; \
        if (((lane >> 5) == ((TAU) & 1)) && (o < len)) { \
            const float d2 = (ni + srcn[start + o]) - 2.0f * dotf; \
            const unsigned uu = __float_as_uint(d2); \
            KREG = (d2 < 0.0f) ? ~uu : (uu | 0x80000000u); \
        } \
        __builtin_amdgcn_wave_barrier(); \
    }

// ---------------------------------------------------------------------------
// Kernel 1: both MLP2 encoders + sq norms + group-offset tables.
// ---------------------------------------------------------------------------
__launch_bounds__(256)
__global__ void encode_kernel(const float* __restrict__ x_pfc, const float* __restrict__ x_vtx,
                              const int* __restrict__ bpfc, const int* __restrict__ bvtx,
                              const float* __restrict__ pw1, const float* __restrict__ pb1,
                              const float* __restrict__ pw2, const float* __restrict__ pb2,
                              const float* __restrict__ vw1, const float* __restrict__ vb1,
                              const float* __restrict__ vw2, const float* __restrict__ vb2,
                              float* __restrict__ pfc_enc, float* __restrict__ pfc_norm,
                              float* __restrict__ vtx_enc, float* __restrict__ vtx_norm,
                              int* __restrict__ goff_pfc, int* __restrict__ goff_vtx) {
    __shared__ float h1s[8][32];
    const int t = threadIdx.x;
    const int c = t & 31;
    const int nl = t >> 5;

    if (blockIdx.x == 0) {
        if (t < 33) goff_pfc[t] = lower_bound_i(bpfc, 8192, t);
        else if (t >= 64 && t < 97) goff_vtx[t - 64] = lower_bound_i(bvtx, 2048, t - 64);
    }

    const bool is_pfc = (blockIdx.x < 1024);
    const int node = (is_pfc ? blockIdx.x : (blockIdx.x - 1024)) * 8 + nl;
    const int din = is_pfc ? 7 : 4;
    const float* __restrict__ xin = is_pfc ? (x_pfc + node * 7) : (x_vtx + node * 4);
    const float* __restrict__ w1 = is_pfc ? pw1 : vw1;
    const float* __restrict__ b1 = is_pfc ? pb1 : vb1;
    const float* __restrict__ w2 = is_pfc ? pw2 : vw2;
    const float* __restrict__ b2 = is_pfc ? pb2 : vb2;
    float* __restrict__ enc  = is_pfc ? pfc_enc : vtx_enc;
    float* __restrict__ nrm  = is_pfc ? pfc_norm : vtx_norm;

    float h1 = b1[c];
    for (int d = 0; d < din; ++d) h1 = fmaf(xin[d], w1[d * 32 + c], h1);
    h1 = LRELU(h1);
    h1s[nl][c] = h1;
    __syncthreads();

    float h2 = b2[c];
#pragma unroll
    for (int d = 0; d < 32; ++d) h2 = fmaf(h1s[nl][d], w2[d * 32 + c], h2);
    h2 = LRELU(h2);
    enc[node * 32 + c] = h2;

    float s = h2 * h2;
#pragma unroll
    for (int m = 16; m >= 1; m >>= 1) s += __shfl_xor(s, m);
    if (c == 0) nrm[node] = s;
}

// ---------------------------------------------------------------------------
// One wave = one dst node's edge conv. Distances via coalesced LDS tiles
// (round-9 was TA-bound: per-lane row loads = 64 lines/instr). Selection =
// ballot bisection (exact 16th-smallest key + idx-ordered tie prefix =
// lax.top_k semantics). W2 in registers (loaded after selection), W1 from
// block LDS. No block barriers; all scratch LDS wave-private.
// ---------------------------------------------------------------------------
__device__ __forceinline__ float edge_conv_wave(
    float4 xi0, float4 xi1, float4 xi2, float4 xi3,
    float4 xi4, float4 xi5, float4 xi6, float4 xi7, float ni,
    const float* __restrict__ srcf, const float* __restrict__ srcn,
    int start, int len, int Ns,
    const float* __restrict__ W, const float* __restrict__ Bc,
    const float* __restrict__ sW1,
    float* __restrict__ sTileW, float4* __restrict__ sNbrW,
    int* __restrict__ widxW, int lane)
{
    const int h16 = (lane >> 5) * 16;
    const float4 xh0 = (lane >= 32) ? xi4 : xi0;
    const float4 xh1 = (lane >= 32) ? xi5 : xi1;
    const float4 xh2 = (lane >= 32) ? xi6 : xi2;
    const float4 xh3 = (lane >= 32) ? xi7 : xi3;

    // Phase 1: distance keys via coalesced tiles (slot s = tile>>1)
    unsigned k0 = 0xFFFFFFFFu, k1 = 0xFFFFFFFFu, k2 = 0xFFFFFFFFu,
             k3 = 0xFFFFFFFFu, k4 = 0xFFFFFFFFu, k5 = 0xFFFFFFFFu;
    DO_TILE(0, k0)  DO_TILE(1, k0)
    DO_TILE(2, k1)  DO_TILE(3, k1)
    DO_TILE(4, k2)  DO_TILE(5, k2)
    DO_TILE(6, k3)  DO_TILE(7, k3)
    DO_TILE(8, k4)  DO_TILE(9, k4)
    DO_TILE(10, k5) DO_TILE(11, k5)

    // Phase 2: bisect for T = exact 16th smallest key.
    unsigned lo = 0u, hi = 0xFFFFFFFFu;
#pragma unroll 1
    for (int it = 0; it < 32; ++it) {
        unsigned mid = lo + ((hi - lo) >> 1);
        int cnt = __popcll(__ballot(k0 <= mid)) + __popcll(__ballot(k1 <= mid))
                + __popcll(__ballot(k2 <= mid)) + __popcll(__ballot(k3 <= mid))
                + __popcll(__ballot(k4 <= mid)) + __popcll(__ballot(k5 <= mid));
        if (cnt >= 16) hi = mid; else lo = mid + 1;
        if (lo == hi) break;
    }
    const unsigned T = lo;

    // Phase 3: membership + compaction (idx = start + lane + 64*s).
    const int m = __popcll(__ballot(k0 < T)) + __popcll(__ballot(k1 < T))
                + __popcll(__ballot(k2 < T)) + __popcll(__ballot(k3 < T))
                + __popcll(__ballot(k4 < T)) + __popcll(__ballot(k5 < T));
    const int need = 16 - m;
    const unsigned long long e0 = __ballot(k0 == T), e1 = __ballot(k1 == T),
                             e2 = __ballot(k2 == T), e3 = __ballot(k3 == T),
                             e4 = __ballot(k4 == T), e5 = __ballot(k5 == T);
    const unsigned long long below = (1ull << lane) - 1ull;
    const int eq0 = __popcll(e0), eq1 = eq0 + __popcll(e1), eq2 = eq1 + __popcll(e2),
              eq3 = eq2 + __popcll(e3), eq4 = eq3 + __popcll(e4);
    const bool sel0 = (k0 < T) || ((k0 == T) && (__popcll(e0 & below) < need));
    const bool sel1 = (k1 < T) || ((k1 == T) && (eq0 + __popcll(e1 & below) < need));
    const bool sel2 = (k2 < T) || ((k2 == T) && (eq1 + __popcll(e2 & below) < need));
    const bool sel3 = (k3 < T) || ((k3 == T) && (eq2 + __popcll(e3 & below) < need));
    const bool sel4 = (k4 < T) || ((k4 == T) && (eq3 + __popcll(e4 & below) < need));
    const bool sel5 = (k5 < T) || ((k5 == T) && (eq4 + __popcll(e5 & below) < need));
    const unsigned long long s0 = __ballot(sel0), s1 = __ballot(sel1), s2 = __ballot(sel2),
                             s3 = __ballot(sel3), s4 = __ballot(sel4), s5 = __ballot(sel5);
    const int c0 = __popcll(s0), c1 = c0 + __popcll(s1), c2 = c1 + __popcll(s2),
              c3 = c2 + __popcll(s3), c4 = c3 + __popcll(s4);
    if (lane < 16) widxW[lane] = min(start, Ns - 1);   // fallback, len<16 never in practice
    __builtin_amdgcn_wave_barrier();
    if (sel0) widxW[__popcll(s0 & below)] = start + lane;
    if (sel1) widxW[c0 + __popcll(s1 & below)] = start + lane + 64;
    if (sel2) widxW[c1 + __popcll(s2 & below)] = start + lane + 128;
    if (sel3) widxW[c2 + __popcll(s3 & below)] = start + lane + 192;
    if (sel4) widxW[c3 + __popcll(s4 & below)] = start + lane + 256;
    if (sel5) widxW[c4 + __popcll(s5 & below)] = start + lane + 320;
    __builtin_amdgcn_wave_barrier();

    const int c = lane & 31;

    // W2 column (rows 32..63, col c) into 8 float4 regs — loaded AFTER the
    // selection so phase-1 VGPR pressure stays low.
    const float4 w2_0 = make_float4(W[32 * 32 + c], W[33 * 32 + c], W[34 * 32 + c], W[35 * 32 + c]);
    const float4 w2_1 = make_float4(W[36 * 32 + c], W[37 * 32 + c], W[38 * 32 + c], W[39 * 32 + c]);
    const float4 w2_2 = make_float4(W[40 * 32 + c], W[41 * 32 + c], W[42 * 32 + c], W[43 * 32 + c]);
    const float4 w2_3 = make_float4(W[44 * 32 + c], W[45 * 32 + c], W[46 * 32 + c], W[47 * 32 + c]);
    const float4 w2_4 = make_float4(W[48 * 32 + c], W[49 * 32 + c], W[50 * 32 + c], W[51 * 32 + c]);
    const float4 w2_5 = make_float4(W[52 * 32 + c], W[53 * 32 + c], W[54 * 32 + c], W[55 * 32 + c]);
    const float4 w2_6 = make_float4(W[56 * 32 + c], W[57 * 32 + c], W[58 * 32 + c], W[59 * 32 + c]);
    const float4 w2_7 = make_float4(W[60 * 32 + c], W[61 * 32 + c], W[62 * 32 + c], W[63 * 32 + c]);

    // Stage 16 neighbor rows (2 independent global loads/lane), overlapping
    // with the base computation.
    const int n0 = lane >> 3, qq = lane & 7;
    const int n1 = n0 + 8;
    int j0 = widxW[n0]; j0 = ((unsigned)j0 < (unsigned)Ns) ? j0 : 0;
    int j1 = widxW[n1]; j1 = ((unsigned)j1 < (unsigned)Ns) ? j1 : 0;
    const float4 v0 = reinterpret_cast<const float4*>(srcf + (size_t)j0 * 32)[qq];
    const float4 v1 = reinterpret_cast<const float4*>(srcf + (size_t)j1 * 32)[qq];

    float base = Bc[c];                     // W1 from block LDS (conflict-free)
    base = wdot4(sW1, c, 0, xi0, base); base = wdot4(sW1, c, 1, xi1, base);
    base = wdot4(sW1, c, 2, xi2, base); base = wdot4(sW1, c, 3, xi3, base);
    base = wdot4(sW1, c, 4, xi4, base); base = wdot4(sW1, c, 5, xi5, base);
    base = wdot4(sW1, c, 6, xi6, base); base = wdot4(sW1, c, 7, xi7, base);
    float bx2 = 0.0f;                       // xi · W2
    bx2 = dot4(xi0, w2_0, bx2); bx2 = dot4(xi1, w2_1, bx2);
    bx2 = dot4(xi2, w2_2, bx2); bx2 = dot4(xi3, w2_3, bx2);
    bx2 = dot4(xi4, w2_4, bx2); bx2 = dot4(xi5, w2_5, bx2);
    bx2 = dot4(xi6, w2_6, bx2); bx2 = dot4(xi7, w2_7, bx2);
    const float cbase = base - bx2;         // h = cbase + nb·W2

    sNbrW[n0 * 8 + qq] = v0;
    sNbrW[n1 * 8 + qq] = v1;
    __builtin_amdgcn_wave_barrier();

    // Conv: two neighbors per round (half-wave each); 32 reg-fma per neighbor.
    const int half = lane >> 5;
    float vmax = -__builtin_huge_valf();
#pragma unroll 1
    for (int r = 0; r < 8; ++r) {
        const float4* nb = sNbrW + (2 * r + half) * 8;
        float acc = cbase;
        acc = dot4(nb[0], w2_0, acc); acc = dot4(nb[1], w2_1, acc);
        acc = dot4(nb[2], w2_2, acc); acc = dot4(nb[3], w2_3, acc);
        acc = dot4(nb[4], w2_4, acc); acc = dot4(nb[5], w2_5, acc);
        acc = dot4(nb[6], w2_6, acc); acc = dot4(nb[7], w2_7, acc);
        vmax = fmaxf(vmax, LRELU(acc));
    }
    vmax = fmaxf(vmax, __shfl_xor(vmax, 32));
    return vmax;   // every lane holds channel (lane&31)'s value
}

// ---------------------------------------------------------------------------
// Kernel 2: fused conv1 + conv2, one wave per node. One block barrier total
// (W1 staging); everything else wave-private.
// ---------------------------------------------------------------------------
__launch_bounds__(256)
__global__ void fused_conv_kernel(
    const float* __restrict__ pfc_enc, const float* __restrict__ n_pfc,
    const float* __restrict__ vtx_enc, const float* __restrict__ n_vtx,
    const int* __restrict__ bpfc,
    const int* __restrict__ goff_pfc, const int* __restrict__ goff_vtx,
    const float* __restrict__ W, const float* __restrict__ Bc,
    float* __restrict__ feats2)
{
    __shared__ float sW1[1024];                          // W rows 0..31
    __shared__ __align__(16) float sTile[4][32 * 33];    // wave-private dist tiles
    __shared__ __align__(16) float4 sNbr[4][128];
    __shared__ int widx[4][16];
    __shared__ __align__(16) float sRow[4][32];

    const int t = threadIdx.x;
    const int lane = t & 63;
    const int w = t >> 6;
    const int i = blockIdx.x * 4 + w;   // grid covers 8192 exactly

    for (int k = t; k < 1024; k += 256) sW1[k] = W[k];
    __syncthreads();   // the only block barrier

    float* sTileW = &sTile[w][0];
    float4* sNbrW = &sNbr[w][0];
    int* widxW = &widx[w][0];

    const int g = bpfc[i];

    // ---- conv1: src = dst = pfc_enc (group ~256±16) ----
    const float4* xr = reinterpret_cast<const float4*>(pfc_enc + (size_t)i * 32);
    const float4 xi0 = xr[0], xi1 = xr[1], xi2 = xr[2], xi3 = xr[3],
                 xi4 = xr[4], xi5 = xr[5], xi6 = xr[6], xi7 = xr[7];
    const int s1 = goff_pfc[g];
    const int len1 = min(goff_pfc[g + 1] - s1, 384);
    float v1 = edge_conv_wave(xi0, xi1, xi2, xi3, xi4, xi5, xi6, xi7, n_pfc[i],
                              pfc_enc, n_pfc, s1, len1, 8192, W, Bc, sW1,
                              sTileW, sNbrW, widxW, lane);

    if (lane < 32) sRow[w][lane] = v1;
    float nf1 = v1 * v1;
#pragma unroll
    for (int m = 16; m >= 1; m >>= 1) nf1 += __shfl_xor(nf1, m);  // |feats1_i|^2
    __builtin_amdgcn_wave_barrier();

    // ---- conv2: dst = feats1 row (wave-private LDS), src = vtx_enc (~64±8) ----
    const float4* fr = reinterpret_cast<const float4*>(&sRow[w][0]);
    const float4 y0 = fr[0], y1 = fr[1], y2 = fr[2], y3 = fr[3],
                 y4 = fr[4], y5 = fr[5], y6 = fr[6], y7 = fr[7];
    const int s2 = goff_vtx[g];
    const int len2 = min(goff_vtx[g + 1] - s2, 384);
    float v2 = edge_conv_wave(y0, y1, y2, y3, y4, y5, y6, y7, nf1,
                              vtx_enc, n_vtx, s2, len2, 2048, W, Bc, sW1,
                              sTileW, sNbrW, widxW, lane);

    if (lane < 32) feats2[(size_t)i * 32 + lane] = v2;
}

// ---------------------------------------------------------------------------
// Kernel 3: output MLP 32 -> 64 -> 32 -> 4 -> 1 (lrelu each) + batch copy.
// ---------------------------------------------------------------------------
__launch_bounds__(256)
__global__ void out_mlp_kernel(const float* __restrict__ f2, const int* __restrict__ bpfc,
                               const float* __restrict__ w1, const float* __restrict__ b1,
                               const float* __restrict__ w2, const float* __restrict__ b2,
                               const float* __restrict__ w3, const float* __restrict__ b3,
                               const float* __restrict__ w4, const float* __restrict__ b4,
                               float* __restrict__ dout, int N) {
    __shared__ float sW1[32 * 64], sW2[64 * 32], sW3[32 * 4];
    __shared__ float sB1[64], sB2[32], sB3[4], sW4[4], sB4[1];
    __shared__ float ex1[4][64];
    __shared__ float ex2[4][32];

    const int t = threadIdx.x;
    for (int k = t; k < 2048; k += 256) { sW1[k] = w1[k]; sW2[k] = w2[k]; }
    if (t < 128) sW3[t] = w3[t];
    if (t < 64)  sB1[t] = b1[t];
    if (t < 32)  sB2[t] = b2[t];
    if (t < 4)   { sB3[t] = b3[t]; sW4[t] = w4[t]; }
    if (t == 0)  sB4[0] = b4[0];
    __syncthreads();

    const int w = t >> 6;
    const int lane = t & 63;
    const int i = blockIdx.x * 4 + w;

    const float* fr = f2 + (size_t)i * 32;

    float h1 = sB1[lane];
#pragma unroll
    for (int d = 0; d < 32; ++d) h1 = fmaf(fr[d], sW1[d * 64 + lane], h1);
    h1 = LRELU(h1);
    ex1[w][lane] = h1;
    __syncthreads();

    const int c = lane & 31;
    float h2 = sB2[c];
#pragma unroll
    for (int d = 0; d < 64; ++d) h2 = fmaf(ex1[w][d], sW2[d * 32 + c], h2);
    h2 = LRELU(h2);
    if (lane < 32) ex2[w][c] = h2;
    __syncthreads();

    float a0 = sB3[0], a1 = sB3[1], a2 = sB3[2], a3 = sB3[3];
#pragma unroll
    for (int d = 0; d < 32; ++d) {
        float e = ex2[w][d];
        a0 = fmaf(e, sW3[d * 4 + 0], a0);
        a1 = fmaf(e, sW3[d * 4 + 1], a1);
        a2 = fmaf(e, sW3[d * 4 + 2], a2);
        a3 = fmaf(e, sW3[d * 4 + 3], a3);
    }
    a0 = LRELU(a0); a1 = LRELU(a1); a2 = LRELU(a2); a3 = LRELU(a3);
    float o = sB4[0];
    o = fmaf(a0, sW4[0], o); o = fmaf(a1, sW4[1], o);
    o = fmaf(a2, sW4[2], o); o = fmaf(a3, sW4[3], o);
    o = LRELU(o);

    if (lane == 0) dout[i] = o;                       // output 0: (8192,1)
    if (lane == 1) dout[N + i] = (float)bpfc[i];      // output 1: batch_pfc
}

// ---------------------------------------------------------------------------
extern "C" void kernel_launch(void* const* d_in, const int* in_sizes, int n_in,
                              void* d_out, int out_size, void* d_ws, size_t ws_size,
                              hipStream_t stream) {
    const float* x_pfc     = (const float*)d_in[0];
    const float* x_vtx     = (const float*)d_in[1];
    const int*   batch_pfc = (const int*)d_in[2];
    const int*   batch_vtx = (const int*)d_in[3];
    const float* pfc_w1 = (const float*)d_in[4];
    const float* pfc_b1 = (const float*)d_in[5];
    const float* pfc_w2 = (const float*)d_in[6];
    const float* pfc_b2 = (const float*)d_in[7];
    const float* vtx_w1 = (const float*)d_in[8];
    const float* vtx_b1 = (const float*)d_in[9];
    const float* vtx_w2 = (const float*)d_in[10];
    const float* vtx_b2 = (const float*)d_in[11];
    const float* conv_w = (const float*)d_in[12];
    const float* conv_b = (const float*)d_in[13];
    const float* out_w1 = (const float*)d_in[14];
    const float* out_b1 = (const float*)d_in[15];
    const float* out_w2 = (const float*)d_in[16];
    const float* out_b2 = (const float*)d_in[17];
    const float* out_w3 = (const float*)d_in[18];
    const float* out_b3 = (const float*)d_in[19];
    const float* out_w4 = (const float*)d_in[20];
    const float* out_b4 = (const float*)d_in[21];

    const int N_PFC = 8192;

    float* ws = (float*)d_ws;
    float* pfc_enc = ws;                     // 8192*32
    float* vtx_enc = ws + 262144;            // 2048*32
    float* feats2  = ws + 327680;            // 8192*32
    float* n_pfc   = ws + 589824;            // 8192
    float* n_vtx   = ws + 598016;            // 2048
    int*   goff_pfc = (int*)(ws + 600064);   // 33
    int*   goff_vtx = (int*)(ws + 600128);   // 33

    encode_kernel<<<1280, 256, 0, stream>>>(x_pfc, x_vtx, batch_pfc, batch_vtx,
                                            pfc_w1, pfc_b1, pfc_w2, pfc_b2,
                                            vtx_w1, vtx_b1, vtx_w2, vtx_b2,
                                            pfc_enc, n_pfc, vtx_enc, n_vtx,
                                            goff_pfc, goff_vtx);

    fused_conv_kernel<<<2048, 256, 0, stream>>>(pfc_enc, n_pfc, vtx_enc, n_vtx,
                                                batch_pfc, goff_pfc, goff_vtx,
                                                conv_w, conv_b, feats2);

    out_mlp_kernel<<<2048, 256, 0, stream>>>(feats2, batch_pfc,
                                             out_w1, out_b1, out_w2, out_b2,
                                             out_w3, out_b3, out_w4, out_b4,
                                             (float*)d_out, N_PFC);
}

// Round 11
// 197.386 us; speedup vs baseline: 1.0551x; 1.0551x over previous
//
#include <hip/hip_runtime.h>
#include <hip/hip_bf16.h>

#define LRELU(val) ((val) >= 0.0f ? (val) : 0.01f * (val))

__device__ __forceinline__ float dot4(float4 a, float4 b, float acc) {
    return fmaf(a.x, b.x, fmaf(a.y, b.y, fmaf(a.z, b.z, fmaf(a.w, b.w, acc))));
}

// acc += quad `a` dotted with rows (4q..4q+3), column c, of a 32-col row-major slab
__device__ __forceinline__ float wdot4(const float* __restrict__ wbase, int c, int q,
                                       float4 a, float acc) {
    acc = fmaf(a.x, wbase[(4 * q + 0) * 32 + c], acc);
    acc = fmaf(a.y, wbase[(4 * q + 1) * 32 + c], acc);
    acc = fmaf(a.z, wbase[(4 * q + 2) * 32 + c], acc);
    acc = fmaf(a.w, wbase[(4 * q + 3) * 32 + c], acc);
    return acc;
}

__device__ inline int lower_bound_i(const int* __restrict__ a, int n, int v) {
    int lo = 0, hi = n;
    while (lo < hi) {
        int m = (lo + hi) >> 1;
        if (a[m] < v) lo = m + 1; else hi = m;
    }
    return lo;
}

// Sortable 32-bit distance key for candidate slot s (named-register resident).
__device__ __forceinline__ unsigned slot_key(
    int s, int lane, int start, int len, int Ns,
    const float* __restrict__ srcf, const float* __restrict__ srcn, float ni,
    float4 xi0, float4 xi1, float4 xi2, float4 xi3,
    float4 xi4, float4 xi5, float4 xi6, float4 xi7)
{
    const int o = lane + 64 * s;
    const bool valid = o < len;
    const int j = valid ? (start + o) : min(start, Ns - 1);
    const float4* rr = reinterpret_cast<const float4*>(srcf + (size_t)j * 32);
    float dot = 0.0f;
    dot = dot4(rr[0], xi0, dot); dot = dot4(rr[1], xi1, dot);
    dot = dot4(rr[2], xi2, dot); dot = dot4(rr[3], xi3, dot);
    dot = dot4(rr[4], xi4, dot); dot = dot4(rr[5], xi5, dot);
    dot = dot4(rr[6], xi6, dot); dot = dot4(rr[7], xi7, dot);
    float d2 = (ni + srcn[j]) - 2.0f * dot;   // reference distance formula
    unsigned u = __float_as_uint(d2);
    u = (d2 < 0.0f) ? ~u : (u | 0x80000000u); // monotone float->uint map
    return valid ? u : 0xFFFFFFFFu;           // invalid slots never selected
}

// ---------------------------------------------------------------------------
// Kernel 1: both MLP2 encoders + sq norms + group-offset tables.
// ---------------------------------------------------------------------------
__launch_bounds__(256)
__global__ void encode_kernel(const float* __restrict__ x_pfc, const float* __restrict__ x_vtx,
                              const int* __restrict__ bpfc, const int* __restrict__ bvtx,
                              const float* __restrict__ pw1, const float* __restrict__ pb1,
                              const float* __restrict__ pw2, const float* __restrict__ pb2,
                              const float* __restrict__ vw1, const float* __restrict__ vb1,
                              const float* __restrict__ vw2, const float* __restrict__ vb2,
                              float* __restrict__ pfc_enc, float* __restrict__ pfc_norm,
                              float* __restrict__ vtx_enc, float* __restrict__ vtx_norm,
                              int* __restrict__ goff_pfc, int* __restrict__ goff_vtx) {
    __shared__ float h1s[8][32];
    const int t = threadIdx.x;
    const int c = t & 31;
    const int nl = t >> 5;

    if (blockIdx.x == 0) {
        if (t < 33) goff_pfc[t] = lower_bound_i(bpfc, 8192, t);
        else if (t >= 64 && t < 97) goff_vtx[t - 64] = lower_bound_i(bvtx, 2048, t - 64);
    }

    const bool is_pfc = (blockIdx.x < 1024);
    const int node = (is_pfc ? blockIdx.x : (blockIdx.x - 1024)) * 8 + nl;
    const int din = is_pfc ? 7 : 4;
    const float* __restrict__ xin = is_pfc ? (x_pfc + node * 7) : (x_vtx + node * 4);
    const float* __restrict__ w1 = is_pfc ? pw1 : vw1;
    const float* __restrict__ b1 = is_pfc ? pb1 : vb1;
    const float* __restrict__ w2 = is_pfc ? pw2 : vw2;
    const float* __restrict__ b2 = is_pfc ? pb2 : vb2;
    float* __restrict__ enc  = is_pfc ? pfc_enc : vtx_enc;
    float* __restrict__ nrm  = is_pfc ? pfc_norm : vtx_norm;

    float h1 = b1[c];
    for (int d = 0; d < din; ++d) h1 = fmaf(xin[d], w1[d * 32 + c], h1);
    h1 = LRELU(h1);
    h1s[nl][c] = h1;
    __syncthreads();

    float h2 = b2[c];
#pragma unroll
    for (int d = 0; d < 32; ++d) h2 = fmaf(h1s[nl][d], w2[d * 32 + c], h2);
    h2 = LRELU(h2);
    enc[node * 32 + c] = h2;

    float s = h2 * h2;
#pragma unroll
    for (int m = 16; m >= 1; m >>= 1) s += __shfl_xor(s, m);
    if (c == 0) nrm[node] = s;
}

// ---------------------------------------------------------------------------
// One wave = one dst node's edge conv (R9 structure — best measured).
// Selection = ballot bisection: keys in <=6 named VGPRs/lane, T = exact 16th
// smallest, membership = k<T plus idx-ordered prefix among k==T (exact
// lax.top_k tie semantics), compaction via ballot prefix counts. W2 in
// registers (loaded after selection). All scratch LDS wave-private, no
// block barriers.
// ---------------------------------------------------------------------------
__device__ __forceinline__ float edge_conv_wave(
    float4 xi0, float4 xi1, float4 xi2, float4 xi3,
    float4 xi4, float4 xi5, float4 xi6, float4 xi7, float ni,
    const float* __restrict__ srcf, const float* __restrict__ srcn,
    int start, int len, int Ns,
    const float* __restrict__ W, const float* __restrict__ Bc,
    float4* __restrict__ sNbrW, int* __restrict__ widxW, int lane)
{
    // Phase 1: distance keys (named regs; slots uniformly skipped past len)
    unsigned k0 = 0xFFFFFFFFu, k1 = 0xFFFFFFFFu, k2 = 0xFFFFFFFFu,
             k3 = 0xFFFFFFFFu, k4 = 0xFFFFFFFFu, k5 = 0xFFFFFFFFu;
    if (len > 0)   k0 = slot_key(0, lane, start, len, Ns, srcf, srcn, ni, xi0, xi1, xi2, xi3, xi4, xi5, xi6, xi7);
    if (len > 64)  k1 = slot_key(1, lane, start, len, Ns, srcf, srcn, ni, xi0, xi1, xi2, xi3, xi4, xi5, xi6, xi7);
    if (len > 128) k2 = slot_key(2, lane, start, len, Ns, srcf, srcn, ni, xi0, xi1, xi2, xi3, xi4, xi5, xi6, xi7);
    if (len > 192) k3 = slot_key(3, lane, start, len, Ns, srcf, srcn, ni, xi0, xi1, xi2, xi3, xi4, xi5, xi6, xi7);
    if (len > 256) k4 = slot_key(4, lane, start, len, Ns, srcf, srcn, ni, xi0, xi1, xi2, xi3, xi4, xi5, xi6, xi7);
    if (len > 320) k5 = slot_key(5, lane, start, len, Ns, srcf, srcn, ni, xi0, xi1, xi2, xi3, xi4, xi5, xi6, xi7);

    // Phase 2: bisect for T = exact 16th smallest key (scalar state).
    unsigned lo = 0u, hi = 0xFFFFFFFFu;
#pragma unroll 1
    for (int it = 0; it < 32; ++it) {
        unsigned mid = lo + ((hi - lo) >> 1);
        int cnt = __popcll(__ballot(k0 <= mid)) + __popcll(__ballot(k1 <= mid))
                + __popcll(__ballot(k2 <= mid)) + __popcll(__ballot(k3 <= mid))
                + __popcll(__ballot(k4 <= mid)) + __popcll(__ballot(k5 <= mid));
        if (cnt >= 16) hi = mid; else lo = mid + 1;
        if (lo == hi) break;
    }
    const unsigned T = lo;

    // Phase 3: membership + compaction (idx = start + lane + 64*s, s-major).
    const int m = __popcll(__ballot(k0 < T)) + __popcll(__ballot(k1 < T))
                + __popcll(__ballot(k2 < T)) + __popcll(__ballot(k3 < T))
                + __popcll(__ballot(k4 < T)) + __popcll(__ballot(k5 < T));
    const int need = 16 - m;
    const unsigned long long e0 = __ballot(k0 == T), e1 = __ballot(k1 == T),
                             e2 = __ballot(k2 == T), e3 = __ballot(k3 == T),
                             e4 = __ballot(k4 == T), e5 = __ballot(k5 == T);
    const unsigned long long below = (1ull << lane) - 1ull;
    const int eq0 = __popcll(e0), eq1 = eq0 + __popcll(e1), eq2 = eq1 + __popcll(e2),
              eq3 = eq2 + __popcll(e3), eq4 = eq3 + __popcll(e4);
    const bool sel0 = (k0 < T) || ((k0 == T) && (__popcll(e0 & below) < need));
    const bool sel1 = (k1 < T) || ((k1 == T) && (eq0 + __popcll(e1 & below) < need));
    const bool sel2 = (k2 < T) || ((k2 == T) && (eq1 + __popcll(e2 & below) < need));
    const bool sel3 = (k3 < T) || ((k3 == T) && (eq2 + __popcll(e3 & below) < need));
    const bool sel4 = (k4 < T) || ((k4 == T) && (eq3 + __popcll(e4 & below) < need));
    const bool sel5 = (k5 < T) || ((k5 == T) && (eq4 + __popcll(e5 & below) < need));
    const unsigned long long s0 = __ballot(sel0), s1 = __ballot(sel1), s2 = __ballot(sel2),
                             s3 = __ballot(sel3), s4 = __ballot(sel4), s5 = __ballot(sel5);
    const int c0 = __popcll(s0), c1 = c0 + __popcll(s1), c2 = c1 + __popcll(s2),
              c3 = c2 + __popcll(s3), c4 = c3 + __popcll(s4);
    (void)s5;
    if (lane < 16) widxW[lane] = min(start, Ns - 1);   // fallback, len<16 never in practice
    __builtin_amdgcn_wave_barrier();
    if (sel0) widxW[__popcll(s0 & below)] = start + lane;
    if (sel1) widxW[c0 + __popcll(s1 & below)] = start + lane + 64;
    if (sel2) widxW[c1 + __popcll(s2 & below)] = start + lane + 128;
    if (sel3) widxW[c2 + __popcll(s3 & below)] = start + lane + 192;
    if (sel4) widxW[c3 + __popcll(s4 & below)] = start + lane + 256;
    if (sel5) widxW[c4 + __popcll(s5 & below)] = start + lane + 320;
    __builtin_amdgcn_wave_barrier();

    const int c = lane & 31;

    // W2 column (rows 32..63, col c) into 8 float4 regs — loaded after the
    // selection so phase-1 VGPR pressure stays low. L2-hot broadcast.
    const float4 w2_0 = make_float4(W[32 * 32 + c], W[33 * 32 + c], W[34 * 32 + c], W[35 * 32 + c]);
    const float4 w2_1 = make_float4(W[36 * 32 + c], W[37 * 32 + c], W[38 * 32 + c], W[39 * 32 + c]);
    const float4 w2_2 = make_float4(W[40 * 32 + c], W[41 * 32 + c], W[42 * 32 + c], W[43 * 32 + c]);
    const float4 w2_3 = make_float4(W[44 * 32 + c], W[45 * 32 + c], W[46 * 32 + c], W[47 * 32 + c]);
    const float4 w2_4 = make_float4(W[48 * 32 + c], W[49 * 32 + c], W[50 * 32 + c], W[51 * 32 + c]);
    const float4 w2_5 = make_float4(W[52 * 32 + c], W[53 * 32 + c], W[54 * 32 + c], W[55 * 32 + c]);
    const float4 w2_6 = make_float4(W[56 * 32 + c], W[57 * 32 + c], W[58 * 32 + c], W[59 * 32 + c]);
    const float4 w2_7 = make_float4(W[60 * 32 + c], W[61 * 32 + c], W[62 * 32 + c], W[63 * 32 + c]);

    // Stage 16 neighbor rows (2 independent global loads/lane), overlapping
    // with the base computation.
    const int n0 = lane >> 3, qq = lane & 7;
    const int n1 = n0 + 8;
    int j0 = widxW[n0]; j0 = ((unsigned)j0 < (unsigned)Ns) ? j0 : 0;
    int j1 = widxW[n1]; j1 = ((unsigned)j1 < (unsigned)Ns) ? j1 : 0;
    const float4 v0 = reinterpret_cast<const float4*>(srcf + (size_t)j0 * 32)[qq];
    const float4 v1 = reinterpret_cast<const float4*>(srcf + (size_t)j1 * 32)[qq];

    float base = Bc[c];                           // W rows 0..31 from global (L2-hot)
    base = wdot4(W, c, 0, xi0, base); base = wdot4(W, c, 1, xi1, base);
    base = wdot4(W, c, 2, xi2, base); base = wdot4(W, c, 3, xi3, base);
    base = wdot4(W, c, 4, xi4, base); base = wdot4(W, c, 5, xi5, base);
    base = wdot4(W, c, 6, xi6, base); base = wdot4(W, c, 7, xi7, base);
    float bx2 = 0.0f;                             // xi · W2 (register-resident weights)
    bx2 = dot4(xi0, w2_0, bx2); bx2 = dot4(xi1, w2_1, bx2);
    bx2 = dot4(xi2, w2_2, bx2); bx2 = dot4(xi3, w2_3, bx2);
    bx2 = dot4(xi4, w2_4, bx2); bx2 = dot4(xi5, w2_5, bx2);
    bx2 = dot4(xi6, w2_6, bx2); bx2 = dot4(xi7, w2_7, bx2);
    const float cbase = base - bx2;               // h = cbase + nb·W2

    sNbrW[n0 * 8 + qq] = v0;
    sNbrW[n1 * 8 + qq] = v1;
    __builtin_amdgcn_wave_barrier();

    // Conv: two neighbors per round (half-wave each); 32 reg-fma per neighbor.
    const int half = lane >> 5;
    float vmax = -__builtin_huge_valf();
#pragma unroll 1
    for (int r = 0; r < 8; ++r) {
        const float4* nb = sNbrW + (2 * r + half) * 8;
        float acc = cbase;
        acc = dot4(nb[0], w2_0, acc); acc = dot4(nb[1], w2_1, acc);
        acc = dot4(nb[2], w2_2, acc); acc = dot4(nb[3], w2_3, acc);
        acc = dot4(nb[4], w2_4, acc); acc = dot4(nb[5], w2_5, acc);
        acc = dot4(nb[6], w2_6, acc); acc = dot4(nb[7], w2_7, acc);
        vmax = fmaxf(vmax, LRELU(acc));
    }
    vmax = fmaxf(vmax, __shfl_xor(vmax, 32));
    return vmax;   // every lane holds channel (lane&31)'s value
}

// ---------------------------------------------------------------------------
// Kernel 2: fused conv1 + conv2. 128-thread blocks = 2 fully independent
// waves, ZERO block barriers (R10's lesson: the limiter was wave residency,
// not memory lines — small blocks let the scheduler pack waves freely).
// ---------------------------------------------------------------------------
__launch_bounds__(128)
__global__ void fused_conv_kernel(
    const float* __restrict__ pfc_enc, const float* __restrict__ n_pfc,
    const float* __restrict__ vtx_enc, const float* __restrict__ n_vtx,
    const int* __restrict__ bpfc,
    const int* __restrict__ goff_pfc, const int* __restrict__ goff_vtx,
    const float* __restrict__ W, const float* __restrict__ Bc,
    float* __restrict__ feats2)
{
    __shared__ __align__(16) float4 sNbr[2][128];
    __shared__ int widx[2][16];
    __shared__ __align__(16) float sRow[2][32];

    const int t = threadIdx.x;
    const int lane = t & 63;
    const int w = t >> 6;
    const int i = blockIdx.x * 2 + w;   // grid covers 8192 exactly

    float4* sNbrW = &sNbr[w][0];
    int* widxW = &widx[w][0];

    const int g = bpfc[i];

    // ---- conv1: src = dst = pfc_enc (group ~256±16) ----
    const float4* xr = reinterpret_cast<const float4*>(pfc_enc + (size_t)i * 32);
    const float4 xi0 = xr[0], xi1 = xr[1], xi2 = xr[2], xi3 = xr[3],
                 xi4 = xr[4], xi5 = xr[5], xi6 = xr[6], xi7 = xr[7];
    const int s1 = goff_pfc[g];
    const int len1 = min(goff_pfc[g + 1] - s1, 384);
    float v1 = edge_conv_wave(xi0, xi1, xi2, xi3, xi4, xi5, xi6, xi7, n_pfc[i],
                              pfc_enc, n_pfc, s1, len1, 8192, W, Bc,
                              sNbrW, widxW, lane);

    if (lane < 32) sRow[w][lane] = v1;
    float nf1 = v1 * v1;
#pragma unroll
    for (int m = 16; m >= 1; m >>= 1) nf1 += __shfl_xor(nf1, m);  // |feats1_i|^2
    __builtin_amdgcn_wave_barrier();

    // ---- conv2: dst = feats1 row (wave-private LDS), src = vtx_enc (~64±8) ----
    const float4* fr = reinterpret_cast<const float4*>(&sRow[w][0]);
    const float4 y0 = fr[0], y1 = fr[1], y2 = fr[2], y3 = fr[3],
                 y4 = fr[4], y5 = fr[5], y6 = fr[6], y7 = fr[7];
    const int s2 = goff_vtx[g];
    const int len2 = min(goff_vtx[g + 1] - s2, 384);
    float v2 = edge_conv_wave(y0, y1, y2, y3, y4, y5, y6, y7, nf1,
                              vtx_enc, n_vtx, s2, len2, 2048, W, Bc,
                              sNbrW, widxW, lane);

    if (lane < 32) feats2[(size_t)i * 32 + lane] = v2;
}

// ---------------------------------------------------------------------------
// Kernel 3: output MLP 32 -> 64 -> 32 -> 4 -> 1 (lrelu each) + batch copy.
// ---------------------------------------------------------------------------
__launch_bounds__(256)
__global__ void out_mlp_kernel(const float* __restrict__ f2, const int* __restrict__ bpfc,
                               const float* __restrict__ w1, const float* __restrict__ b1,
                               const float* __restrict__ w2, const float* __restrict__ b2,
                               const float* __restrict__ w3, const float* __restrict__ b3,
                               const float* __restrict__ w4, const float* __restrict__ b4,
                               float* __restrict__ dout, int N) {
    __shared__ float sW1[32 * 64], sW2[64 * 32], sW3[32 * 4];
    __shared__ float sB1[64], sB2[32], sB3[4], sW4[4], sB4[1];
    __shared__ float ex1[4][64];
    __shared__ float ex2[4][32];

    const int t = threadIdx.x;
    for (int k = t; k < 2048; k += 256) { sW1[k] = w1[k]; sW2[k] = w2[k]; }
    if (t < 128) sW3[t] = w3[t];
    if (t < 64)  sB1[t] = b1[t];
    if (t < 32)  sB2[t] = b2[t];
    if (t < 4)   { sB3[t] = b3[t]; sW4[t] = w4[t]; }
    if (t == 0)  sB4[0] = b4[0];
    __syncthreads();

    const int w = t >> 6;
    const int lane = t & 63;
    const int i = blockIdx.x * 4 + w;

    const float* fr = f2 + (size_t)i * 32;

    float h1 = sB1[lane];
#pragma unroll
    for (int d = 0; d < 32; ++d) h1 = fmaf(fr[d], sW1[d * 64 + lane], h1);
    h1 = LRELU(h1);
    ex1[w][lane] = h1;
    __syncthreads();

    const int c = lane & 31;
    float h2 = sB2[c];
#pragma unroll
    for (int d = 0; d < 64; ++d) h2 = fmaf(ex1[w][d], sW2[d * 32 + c], h2);
    h2 = LRELU(h2);
    if (lane < 32) ex2[w][c] = h2;
    __syncthreads();

    float a0 = sB3[0], a1 = sB3[1], a2 = sB3[2], a3 = sB3[3];
#pragma unroll
    for (int d = 0; d < 32; ++d) {
        float e = ex2[w][d];
        a0 = fmaf(e, sW3[d * 4 + 0], a0);
        a1 = fmaf(e, sW3[d * 4 + 1], a1);
        a2 = fmaf(e, sW3[d * 4 + 2], a2);
        a3 = fmaf(e, sW3[d * 4 + 3], a3);
    }
    a0 = LRELU(a0); a1 = LRELU(a1); a2 = LRELU(a2); a3 = LRELU(a3);
    float o = sB4[0];
    o = fmaf(a0, sW4[0], o); o = fmaf(a1, sW4[1], o);
    o = fmaf(a2, sW4[2], o); o = fmaf(a3, sW4[3], o);
    o = LRELU(o);

    if (lane == 0) dout[i] = o;                       // output 0: (8192,1)
    if (lane == 1) dout[N + i] = (float)bpfc[i];      // output 1: batch_pfc
}

// ---------------------------------------------------------------------------
extern "C" void kernel_launch(void* const* d_in, const int* in_sizes, int n_in,
                              void* d_out, int out_size, void* d_ws, size_t ws_size,
                              hipStream_t stream) {
    const float* x_pfc     = (const float*)d_in[0];
    const float* x_vtx     = (const float*)d_in[1];
    const int*   batch_pfc = (const int*)d_in[2];
    const int*   batch_vtx = (const int*)d_in[3];
    const float* pfc_w1 = (const float*)d_in[4];
    const float* pfc_b1 = (const float*)d_in[5];
    const float* pfc_w2 = (const float*)d_in[6];
    const float* pfc_b2 = (const float*)d_in[7];
    const float* vtx_w1 = (const float*)d_in[8];
    const float* vtx_b1 = (const float*)d_in[9];
    const float* vtx_w2 = (const float*)d_in[10];
    const float* vtx_b2 = (const float*)d_in[11];
    const float* conv_w = (const float*)d_in[12];
    const float* conv_b = (const float*)d_in[13];
    const float* out_w1 = (const float*)d_in[14];
    const float* out_b1 = (const float*)d_in[15];
    const float* out_w2 = (const float*)d_in[16];
    const float* out_b2 = (const float*)d_in[17];
    const float* out_w3 = (const float*)d_in[18];
    const float* out_b3 = (const float*)d_in[19];
    const float* out_w4 = (const float*)d_in[20];
    const float* out_b4 = (const float*)d_in[21];

    const int N_PFC = 8192;

    float* ws = (float*)d_ws;
    float* pfc_enc = ws;                     // 8192*32
    float* vtx_enc = ws + 262144;            // 2048*32
    float* feats2  = ws + 327680;            // 8192*32
    float* n_pfc   = ws + 589824;            // 8192
    float* n_vtx   = ws + 598016;            // 2048
    int*   goff_pfc = (int*)(ws + 600064);   // 33
    int*   goff_vtx = (int*)(ws + 600128);   // 33

    encode_kernel<<<1280, 256, 0, stream>>>(x_pfc, x_vtx, batch_pfc, batch_vtx,
                                            pfc_w1, pfc_b1, pfc_w2, pfc_b2,
                                            vtx_w1, vtx_b1, vtx_w2, vtx_b2,
                                            pfc_enc, n_pfc, vtx_enc, n_vtx,
                                            goff_pfc, goff_vtx);

    fused_conv_kernel<<<4096, 128, 0, stream>>>(pfc_enc, n_pfc, vtx_enc, n_vtx,
                                                batch_pfc, goff_pfc, goff_vtx,
                                                conv_w, conv_b, feats2);

    out_mlp_kernel<<<2048, 256, 0, stream>>>(feats2, batch_pfc,
                                             out_w1, out_b1, out_w2, out_b2,
                                             out_w3, out_b3, out_w4, out_b4,
                                             (float*)d_out, N_PFC);
}

// Round 12
// 188.649 us; speedup vs baseline: 1.1040x; 1.0463x over previous
//
#include <hip/hip_runtime.h>
#include <hip/hip_bf16.h>

#define LRELU(val) ((val) >= 0.0f ? (val) : 0.01f * (val))

__device__ __forceinline__ float dot4(float4 a, float4 b, float acc) {
    return fmaf(a.x, b.x, fmaf(a.y, b.y, fmaf(a.z, b.z, fmaf(a.w, b.w, acc))));
}

__device__ __forceinline__ float wdot4(const float* __restrict__ wbase, int c, int q,
                                       float4 a, float acc) {
    acc = fmaf(a.x, wbase[(4 * q + 0) * 32 + c], acc);
    acc = fmaf(a.y, wbase[(4 * q + 1) * 32 + c], acc);
    acc = fmaf(a.z, wbase[(4 * q + 2) * 32 + c], acc);
    acc = fmaf(a.w, wbase[(4 * q + 3) * 32 + c], acc);
    return acc;
}

__device__ inline int lower_bound_i(const int* __restrict__ a, int n, int v) {
    int lo = 0, hi = n;
    while (lo < hi) {
        int m = (lo + hi) >> 1;
        if (a[m] < v) lo = m + 1; else hi = m;
    }
    return lo;
}

// Sortable 32-bit distance key for candidate slot s (named-register resident).
__device__ __forceinline__ unsigned slot_key(
    int s, int lane, int start, int len, int Ns,
    const float* __restrict__ srcf, const float* __restrict__ srcn, float ni,
    float4 x0, float4 x1, float4 x2, float4 x3,
    float4 x4, float4 x5, float4 x6, float4 x7)
{
    const int o = lane + 64 * s;
    const bool valid = o < len;
    const int j = valid ? (start + o) : min(start, Ns - 1);
    const float4* rr = reinterpret_cast<const float4*>(srcf + (size_t)j * 32);
    float dot = 0.0f;
    dot = dot4(rr[0], x0, dot); dot = dot4(rr[1], x1, dot);
    dot = dot4(rr[2], x2, dot); dot = dot4(rr[3], x3, dot);
    dot = dot4(rr[4], x4, dot); dot = dot4(rr[5], x5, dot);
    dot = dot4(rr[6], x6, dot); dot = dot4(rr[7], x7, dot);
    float d2 = (ni + srcn[j]) - 2.0f * dot;   // reference distance formula
    unsigned u = __float_as_uint(d2);
    u = (d2 < 0.0f) ? ~u : (u | 0x80000000u); // monotone float->uint map
    return valid ? u : 0xFFFFFFFFu;           // invalid slots never selected
}

// Membership + compaction for one node (exact lax.top_k tie semantics).
template <int NSL>
__device__ __forceinline__ void select_compact(
    unsigned k0, unsigned k1, unsigned k2, unsigned k3, unsigned k4, unsigned k5,
    unsigned T, int start, int Ns, int* __restrict__ widxW, int lane)
{
    const unsigned long long below = (1ull << lane) - 1ull;
    int m = __popcll(__ballot(k0 < T));
    if (NSL > 1) m += __popcll(__ballot(k1 < T));
    if (NSL > 2) m += __popcll(__ballot(k2 < T));
    if (NSL > 3) m += __popcll(__ballot(k3 < T));
    if (NSL > 4) m += __popcll(__ballot(k4 < T));
    if (NSL > 5) m += __popcll(__ballot(k5 < T));
    const int need = 16 - m;
    const unsigned long long e0 = __ballot(k0 == T);
    const unsigned long long e1 = (NSL > 1) ? __ballot(k1 == T) : 0ull;
    const unsigned long long e2 = (NSL > 2) ? __ballot(k2 == T) : 0ull;
    const unsigned long long e3 = (NSL > 3) ? __ballot(k3 == T) : 0ull;
    const unsigned long long e4 = (NSL > 4) ? __ballot(k4 == T) : 0ull;
    const int eq0 = __popcll(e0), eq1 = eq0 + __popcll(e1), eq2 = eq1 + __popcll(e2),
              eq3 = eq2 + __popcll(e3), eq4 = eq3 + __popcll(e4);
    const bool sel0 = (k0 < T) || ((k0 == T) && (__popcll(e0 & below) < need));
    const bool sel1 = (NSL > 1) && ((k1 < T) || ((k1 == T) && (eq0 + __popcll(e1 & below) < need)));
    const bool sel2 = (NSL > 2) && ((k2 < T) || ((k2 == T) && (eq1 + __popcll(e2 & below) < need)));
    const bool sel3 = (NSL > 3) && ((k3 < T) || ((k3 == T) && (eq2 + __popcll(e3 & below) < need)));
    const bool sel4 = (NSL > 4) && ((k4 < T) || ((k4 == T) && (eq3 + __popcll(e4 & below) < need)));
    const bool sel5 = (NSL > 5) && ((k5 < T) || ((k5 == T) && (eq4 + __popcll(__ballot(k5 == T) & below) < need)));
    const unsigned long long s0 = __ballot(sel0);
    const unsigned long long s1 = __ballot(sel1);
    const unsigned long long s2 = __ballot(sel2);
    const unsigned long long s3 = __ballot(sel3);
    const unsigned long long s4 = __ballot(sel4);
    const unsigned long long s5 = __ballot(sel5);
    const int c0 = __popcll(s0), c1 = c0 + __popcll(s1), c2 = c1 + __popcll(s2),
              c3 = c2 + __popcll(s3), c4 = c3 + __popcll(s4);
    if (lane < 16) widxW[lane] = min(start, Ns - 1);   // fallback, len<16 never in practice
    __builtin_amdgcn_wave_barrier();
    if (sel0) widxW[__popcll(s0 & below)] = start + lane;
    if (NSL > 1 && sel1) widxW[c0 + __popcll(s1 & below)] = start + lane + 64;
    if (NSL > 2 && sel2) widxW[c1 + __popcll(s2 & below)] = start + lane + 128;
    if (NSL > 3 && sel3) widxW[c2 + __popcll(s3 & below)] = start + lane + 192;
    if (NSL > 4 && sel4) widxW[c3 + __popcll(s4 & below)] = start + lane + 256;
    if (NSL > 5 && sel5) widxW[c4 + __popcll(s5 & below)] = start + lane + 320;
    __builtin_amdgcn_wave_barrier();
}

// ---------------------------------------------------------------------------
// TWO independent nodes per wave, all phases interleaved (R11 was latency-
// bound: one node's serial chain = scattered loads -> 32-iter bisect -> LDS
// -> conv, ~70% stall at ~1.6 waves/SIMD; pairing doubles intra-wave ILP —
// two bisections share one loop at ~1x wall). NSL-templated (bucket 2/4/6)
// so conv2 (len~64) pays 2 ballots/iter not 6.
// ---------------------------------------------------------------------------
template <int NSL>
__device__ __forceinline__ void conv_pair(
    float4 ax0, float4 ax1, float4 ax2, float4 ax3,
    float4 ax4, float4 ax5, float4 ax6, float4 ax7,
    float niA, int startA, int lenA,
    float4 bx0, float4 bx1, float4 bx2, float4 bx3,
    float4 bx4, float4 bx5, float4 bx6, float4 bx7,
    float niB, int startB, int lenB,
    const float* __restrict__ srcf, const float* __restrict__ srcn, int Ns,
    const float* __restrict__ W, const float* __restrict__ Bc,
    float4 w20, float4 w21, float4 w22, float4 w23,
    float4 w24, float4 w25, float4 w26, float4 w27,
    float4* __restrict__ sNbrA, float4* __restrict__ sNbrB,
    int* __restrict__ widxA, int* __restrict__ widxB,
    int lane, float& vOutA, float& vOutB)
{
    // Phase 1: distance keys for both nodes (independent loads interleave)
    unsigned kA0 = 0xFFFFFFFFu, kA1 = 0xFFFFFFFFu, kA2 = 0xFFFFFFFFu,
             kA3 = 0xFFFFFFFFu, kA4 = 0xFFFFFFFFu, kA5 = 0xFFFFFFFFu;
    unsigned kB0 = 0xFFFFFFFFu, kB1 = 0xFFFFFFFFu, kB2 = 0xFFFFFFFFu,
             kB3 = 0xFFFFFFFFu, kB4 = 0xFFFFFFFFu, kB5 = 0xFFFFFFFFu;
    kA0 = slot_key(0, lane, startA, lenA, Ns, srcf, srcn, niA, ax0, ax1, ax2, ax3, ax4, ax5, ax6, ax7);
    kB0 = slot_key(0, lane, startB, lenB, Ns, srcf, srcn, niB, bx0, bx1, bx2, bx3, bx4, bx5, bx6, bx7);
    if (NSL > 1) {
        if (lenA > 64)  kA1 = slot_key(1, lane, startA, lenA, Ns, srcf, srcn, niA, ax0, ax1, ax2, ax3, ax4, ax5, ax6, ax7);
        if (lenB > 64)  kB1 = slot_key(1, lane, startB, lenB, Ns, srcf, srcn, niB, bx0, bx1, bx2, bx3, bx4, bx5, bx6, bx7);
    }
    if (NSL > 2) {
        if (lenA > 128) kA2 = slot_key(2, lane, startA, lenA, Ns, srcf, srcn, niA, ax0, ax1, ax2, ax3, ax4, ax5, ax6, ax7);
        if (lenB > 128) kB2 = slot_key(2, lane, startB, lenB, Ns, srcf, srcn, niB, bx0, bx1, bx2, bx3, bx4, bx5, bx6, bx7);
    }
    if (NSL > 3) {
        if (lenA > 192) kA3 = slot_key(3, lane, startA, lenA, Ns, srcf, srcn, niA, ax0, ax1, ax2, ax3, ax4, ax5, ax6, ax7);
        if (lenB > 192) kB3 = slot_key(3, lane, startB, lenB, Ns, srcf, srcn, niB, bx0, bx1, bx2, bx3, bx4, bx5, bx6, bx7);
    }
    if (NSL > 4) {
        if (lenA > 256) kA4 = slot_key(4, lane, startA, lenA, Ns, srcf, srcn, niA, ax0, ax1, ax2, ax3, ax4, ax5, ax6, ax7);
        if (lenB > 256) kB4 = slot_key(4, lane, startB, lenB, Ns, srcf, srcn, niB, bx0, bx1, bx2, bx3, bx4, bx5, bx6, bx7);
    }
    if (NSL > 5) {
        if (lenA > 320) kA5 = slot_key(5, lane, startA, lenA, Ns, srcf, srcn, niA, ax0, ax1, ax2, ax3, ax4, ax5, ax6, ax7);
        if (lenB > 320) kB5 = slot_key(5, lane, startB, lenB, Ns, srcf, srcn, niB, bx0, bx1, bx2, bx3, bx4, bx5, bx6, bx7);
    }

    // Phase 2: two bisections in one loop (independent scalar states).
    unsigned loA = 0u, hiA = 0xFFFFFFFFu, loB = 0u, hiB = 0xFFFFFFFFu;
#pragma unroll 1
    for (int it = 0; it < 32; ++it) {
        const unsigned mA = loA + ((hiA - loA) >> 1);
        const unsigned mB = loB + ((hiB - loB) >> 1);
        int cA = __popcll(__ballot(kA0 <= mA));
        int cB = __popcll(__ballot(kB0 <= mB));
        if (NSL > 1) { cA += __popcll(__ballot(kA1 <= mA)); cB += __popcll(__ballot(kB1 <= mB)); }
        if (NSL > 2) { cA += __popcll(__ballot(kA2 <= mA)); cB += __popcll(__ballot(kB2 <= mB)); }
        if (NSL > 3) { cA += __popcll(__ballot(kA3 <= mA)); cB += __popcll(__ballot(kB3 <= mB)); }
        if (NSL > 4) { cA += __popcll(__ballot(kA4 <= mA)); cB += __popcll(__ballot(kB4 <= mB)); }
        if (NSL > 5) { cA += __popcll(__ballot(kA5 <= mA)); cB += __popcll(__ballot(kB5 <= mB)); }
        if (loA != hiA) { if (cA >= 16) hiA = mA; else loA = mA + 1; }
        if (loB != hiB) { if (cB >= 16) hiB = mB; else loB = mB + 1; }
        if (loA == hiA && loB == hiB) break;
    }

    // Phase 3: membership + compaction per node.
    select_compact<NSL>(kA0, kA1, kA2, kA3, kA4, kA5, loA, startA, Ns, widxA, lane);
    select_compact<NSL>(kB0, kB1, kB2, kB3, kB4, kB5, loB, startB, Ns, widxB, lane);

    // Stage 16 neighbor rows per node (4 independent loads/lane total),
    // overlapping with both base computations.
    const int c = lane & 31;
    const int n0 = lane >> 3, qq = lane & 7;
    const int n1 = n0 + 8;
    int jA0 = widxA[n0]; jA0 = ((unsigned)jA0 < (unsigned)Ns) ? jA0 : 0;
    int jA1 = widxA[n1]; jA1 = ((unsigned)jA1 < (unsigned)Ns) ? jA1 : 0;
    int jB0 = widxB[n0]; jB0 = ((unsigned)jB0 < (unsigned)Ns) ? jB0 : 0;
    int jB1 = widxB[n1]; jB1 = ((unsigned)jB1 < (unsigned)Ns) ? jB1 : 0;
    const float4* S = reinterpret_cast<const float4*>(srcf);
    const float4 rA0 = S[(size_t)jA0 * 8 + qq];
    const float4 rA1 = S[(size_t)jA1 * 8 + qq];
    const float4 rB0 = S[(size_t)jB0 * 8 + qq];
    const float4 rB1 = S[(size_t)jB1 * 8 + qq];

    float baseA = Bc[c];
    baseA = wdot4(W, c, 0, ax0, baseA); baseA = wdot4(W, c, 1, ax1, baseA);
    baseA = wdot4(W, c, 2, ax2, baseA); baseA = wdot4(W, c, 3, ax3, baseA);
    baseA = wdot4(W, c, 4, ax4, baseA); baseA = wdot4(W, c, 5, ax5, baseA);
    baseA = wdot4(W, c, 6, ax6, baseA); baseA = wdot4(W, c, 7, ax7, baseA);
    float dA = 0.0f;
    dA = dot4(ax0, w20, dA); dA = dot4(ax1, w21, dA); dA = dot4(ax2, w22, dA); dA = dot4(ax3, w23, dA);
    dA = dot4(ax4, w24, dA); dA = dot4(ax5, w25, dA); dA = dot4(ax6, w26, dA); dA = dot4(ax7, w27, dA);
    const float cbaseA = baseA - dA;

    float baseB = Bc[c];
    baseB = wdot4(W, c, 0, bx0, baseB); baseB = wdot4(W, c, 1, bx1, baseB);
    baseB = wdot4(W, c, 2, bx2, baseB); baseB = wdot4(W, c, 3, bx3, baseB);
    baseB = wdot4(W, c, 4, bx4, baseB); baseB = wdot4(W, c, 5, bx5, baseB);
    baseB = wdot4(W, c, 6, bx6, baseB); baseB = wdot4(W, c, 7, bx7, baseB);
    float dB = 0.0f;
    dB = dot4(bx0, w20, dB); dB = dot4(bx1, w21, dB); dB = dot4(bx2, w22, dB); dB = dot4(bx3, w23, dB);
    dB = dot4(bx4, w24, dB); dB = dot4(bx5, w25, dB); dB = dot4(bx6, w26, dB); dB = dot4(bx7, w27, dB);
    const float cbaseB = baseB - dB;

    sNbrA[n0 * 8 + qq] = rA0;
    sNbrA[n1 * 8 + qq] = rA1;
    sNbrB[n0 * 8 + qq] = rB0;
    sNbrB[n1 * 8 + qq] = rB1;
    __builtin_amdgcn_wave_barrier();

    // Conv rounds, both nodes interleaved; 2 neighbors/round (half-wave each)
    const int half = lane >> 5;
    float vmA = -__builtin_huge_valf(), vmB = -__builtin_huge_valf();
#pragma unroll 1
    for (int r = 0; r < 8; ++r) {
        const float4* nA = sNbrA + (2 * r + half) * 8;
        const float4* nB = sNbrB + (2 * r + half) * 8;
        float accA = cbaseA, accB = cbaseB;
        accA = dot4(nA[0], w20, accA); accB = dot4(nB[0], w20, accB);
        accA = dot4(nA[1], w21, accA); accB = dot4(nB[1], w21, accB);
        accA = dot4(nA[2], w22, accA); accB = dot4(nB[2], w22, accB);
        accA = dot4(nA[3], w23, accA); accB = dot4(nB[3], w23, accB);
        accA = dot4(nA[4], w24, accA); accB = dot4(nB[4], w24, accB);
        accA = dot4(nA[5], w25, accA); accB = dot4(nB[5], w25, accB);
        accA = dot4(nA[6], w26, accA); accB = dot4(nB[6], w26, accB);
        accA = dot4(nA[7], w27, accA); accB = dot4(nB[7], w27, accB);
        vmA = fmaxf(vmA, LRELU(accA));
        vmB = fmaxf(vmB, LRELU(accB));
    }
    vmA = fmaxf(vmA, __shfl_xor(vmA, 32));
    vmB = fmaxf(vmB, __shfl_xor(vmB, 32));
    vOutA = vmA;
    vOutB = vmB;
}

// ---------------------------------------------------------------------------
// Kernel 1: both MLP2 encoders + sq norms + group-offset tables.
// ---------------------------------------------------------------------------
__launch_bounds__(256)
__global__ void encode_kernel(const float* __restrict__ x_pfc, const float* __restrict__ x_vtx,
                              const int* __restrict__ bpfc, const int* __restrict__ bvtx,
                              const float* __restrict__ pw1, const float* __restrict__ pb1,
                              const float* __restrict__ pw2, const float* __restrict__ pb2,
                              const float* __restrict__ vw1, const float* __restrict__ vb1,
                              const float* __restrict__ vw2, const float* __restrict__ vb2,
                              float* __restrict__ pfc_enc, float* __restrict__ pfc_norm,
                              float* __restrict__ vtx_enc, float* __restrict__ vtx_norm,
                              int* __restrict__ goff_pfc, int* __restrict__ goff_vtx) {
    __shared__ float h1s[8][32];
    const int t = threadIdx.x;
    const int c = t & 31;
    const int nl = t >> 5;

    if (blockIdx.x == 0) {
        if (t < 33) goff_pfc[t] = lower_bound_i(bpfc, 8192, t);
        else if (t >= 64 && t < 97) goff_vtx[t - 64] = lower_bound_i(bvtx, 2048, t - 64);
    }

    const bool is_pfc = (blockIdx.x < 1024);
    const int node = (is_pfc ? blockIdx.x : (blockIdx.x - 1024)) * 8 + nl;
    const int din = is_pfc ? 7 : 4;
    const float* __restrict__ xin = is_pfc ? (x_pfc + node * 7) : (x_vtx + node * 4);
    const float* __restrict__ w1 = is_pfc ? pw1 : vw1;
    const float* __restrict__ b1 = is_pfc ? pb1 : vb1;
    const float* __restrict__ w2 = is_pfc ? pw2 : vw2;
    const float* __restrict__ b2 = is_pfc ? pb2 : vb2;
    float* __restrict__ enc  = is_pfc ? pfc_enc : vtx_enc;
    float* __restrict__ nrm  = is_pfc ? pfc_norm : vtx_norm;

    float h1 = b1[c];
    for (int d = 0; d < din; ++d) h1 = fmaf(xin[d], w1[d * 32 + c], h1);
    h1 = LRELU(h1);
    h1s[nl][c] = h1;
    __syncthreads();

    float h2 = b2[c];
#pragma unroll
    for (int d = 0; d < 32; ++d) h2 = fmaf(h1s[nl][d], w2[d * 32 + c], h2);
    h2 = LRELU(h2);
    enc[node * 32 + c] = h2;

    float s = h2 * h2;
#pragma unroll
    for (int m = 16; m >= 1; m >>= 1) s += __shfl_xor(s, m);
    if (c == 0) nrm[node] = s;
}

// ---------------------------------------------------------------------------
// Kernel 2: fused conv1 + conv2, TWO nodes per wave, 128-thr blocks, zero
// block barriers. XCD swizzle: block b -> xcd b&7 owns nodes [xcd*1024, ..)
// so a group's candidate rows stay in one XCD's L2.
// ---------------------------------------------------------------------------
__launch_bounds__(128)
__global__ void fused_conv_kernel(
    const float* __restrict__ pfc_enc, const float* __restrict__ n_pfc,
    const float* __restrict__ vtx_enc, const float* __restrict__ n_vtx,
    const int* __restrict__ bpfc,
    const int* __restrict__ goff_pfc, const int* __restrict__ goff_vtx,
    const float* __restrict__ W, const float* __restrict__ Bc,
    float* __restrict__ feats2)
{
    __shared__ __align__(16) float4 sNbr[2][2][128];   // [wave][node]
    __shared__ int widx[2][2][16];
    __shared__ __align__(16) float sRow[2][2][32];

    const int t = threadIdx.x;
    const int lane = t & 63;
    const int w = t >> 6;
    const int b = blockIdx.x;              // 2048 blocks x 4 nodes
    const int xcd = b & 7, chunk = b >> 3;
    const int iA = xcd * 1024 + chunk * 4 + w * 2;
    const int iB = iA + 1;
    const int c = lane & 31;

    // Hoisted W2 column (rows 32..63, col c) — shared by both convs.
    const float4 w20 = make_float4(W[32 * 32 + c], W[33 * 32 + c], W[34 * 32 + c], W[35 * 32 + c]);
    const float4 w21 = make_float4(W[36 * 32 + c], W[37 * 32 + c], W[38 * 32 + c], W[39 * 32 + c]);
    const float4 w22 = make_float4(W[40 * 32 + c], W[41 * 32 + c], W[42 * 32 + c], W[43 * 32 + c]);
    const float4 w23 = make_float4(W[44 * 32 + c], W[45 * 32 + c], W[46 * 32 + c], W[47 * 32 + c]);
    const float4 w24 = make_float4(W[48 * 32 + c], W[49 * 32 + c], W[50 * 32 + c], W[51 * 32 + c]);
    const float4 w25 = make_float4(W[52 * 32 + c], W[53 * 32 + c], W[54 * 32 + c], W[55 * 32 + c]);
    const float4 w26 = make_float4(W[56 * 32 + c], W[57 * 32 + c], W[58 * 32 + c], W[59 * 32 + c]);
    const float4 w27 = make_float4(W[60 * 32 + c], W[61 * 32 + c], W[62 * 32 + c], W[63 * 32 + c]);

    float4* sNbrA = &sNbr[w][0][0];
    float4* sNbrB = &sNbr[w][1][0];
    int* widxA = &widx[w][0][0];
    int* widxB = &widx[w][1][0];

    const int gA = bpfc[iA], gB = bpfc[iB];

    // ---- conv1: src = dst = pfc_enc (group ~256±16) ----
    const float4* xA = reinterpret_cast<const float4*>(pfc_enc + (size_t)iA * 32);
    const float4 a0 = xA[0], a1 = xA[1], a2 = xA[2], a3 = xA[3],
                 a4 = xA[4], a5 = xA[5], a6 = xA[6], a7 = xA[7];
    const float4* xB = reinterpret_cast<const float4*>(pfc_enc + (size_t)iB * 32);
    const float4 b0 = xB[0], b1 = xB[1], b2 = xB[2], b3 = xB[3],
                 b4 = xB[4], b5 = xB[5], b6 = xB[6], b7 = xB[7];
    const float niA = n_pfc[iA], niB = n_pfc[iB];
    const int s1A = goff_pfc[gA], len1A = min(goff_pfc[gA + 1] - s1A, 384);
    const int s1B = goff_pfc[gB], len1B = min(goff_pfc[gB + 1] - s1B, 384);

    float v1A, v1B;
    {
        const int nsl = (max(len1A, len1B) + 63) >> 6;
        if (nsl <= 2)
            conv_pair<2>(a0, a1, a2, a3, a4, a5, a6, a7, niA, s1A, len1A,
                         b0, b1, b2, b3, b4, b5, b6, b7, niB, s1B, len1B,
                         pfc_enc, n_pfc, 8192, W, Bc,
                         w20, w21, w22, w23, w24, w25, w26, w27,
                         sNbrA, sNbrB, widxA, widxB, lane, v1A, v1B);
        else if (nsl <= 4)
            conv_pair<4>(a0, a1, a2, a3, a4, a5, a6, a7, niA, s1A, len1A,
                         b0, b1, b2, b3, b4, b5, b6, b7, niB, s1B, len1B,
                         pfc_enc, n_pfc, 8192, W, Bc,
                         w20, w21, w22, w23, w24, w25, w26, w27,
                         sNbrA, sNbrB, widxA, widxB, lane, v1A, v1B);
        else
            conv_pair<6>(a0, a1, a2, a3, a4, a5, a6, a7, niA, s1A, len1A,
                         b0, b1, b2, b3, b4, b5, b6, b7, niB, s1B, len1B,
                         pfc_enc, n_pfc, 8192, W, Bc,
                         w20, w21, w22, w23, w24, w25, w26, w27,
                         sNbrA, sNbrB, widxA, widxB, lane, v1A, v1B);
    }

    if (lane < 32) { sRow[w][0][lane] = v1A; sRow[w][1][lane] = v1B; }
    float nfA = v1A * v1A, nfB = v1B * v1B;
#pragma unroll
    for (int m = 16; m >= 1; m >>= 1) { nfA += __shfl_xor(nfA, m); nfB += __shfl_xor(nfB, m); }
    __builtin_amdgcn_wave_barrier();

    // ---- conv2: dst = feats1 rows (wave-private LDS), src = vtx_enc (~64±8) ----
    const float4* fA = reinterpret_cast<const float4*>(&sRow[w][0][0]);
    const float4 ya0 = fA[0], ya1 = fA[1], ya2 = fA[2], ya3 = fA[3],
                 ya4 = fA[4], ya5 = fA[5], ya6 = fA[6], ya7 = fA[7];
    const float4* fB = reinterpret_cast<const float4*>(&sRow[w][1][0]);
    const float4 yb0 = fB[0], yb1 = fB[1], yb2 = fB[2], yb3 = fB[3],
                 yb4 = fB[4], yb5 = fB[5], yb6 = fB[6], yb7 = fB[7];
    const int s2A = goff_vtx[gA], len2A = min(goff_vtx[gA + 1] - s2A, 384);
    const int s2B = goff_vtx[gB], len2B = min(goff_vtx[gB + 1] - s2B, 384);

    float v2A, v2B;
    {
        const int nsl = (max(len2A, len2B) + 63) >> 6;
        if (nsl <= 2)
            conv_pair<2>(ya0, ya1, ya2, ya3, ya4, ya5, ya6, ya7, nfA, s2A, len2A,
                         yb0, yb1, yb2, yb3, yb4, yb5, yb6, yb7, nfB, s2B, len2B,
                         vtx_enc, n_vtx, 2048, W, Bc,
                         w20, w21, w22, w23, w24, w25, w26, w27,
                         sNbrA, sNbrB, widxA, widxB, lane, v2A, v2B);
        else if (nsl <= 4)
            conv_pair<4>(ya0, ya1, ya2, ya3, ya4, ya5, ya6, ya7, nfA, s2A, len2A,
                         yb0, yb1, yb2, yb3, yb4, yb5, yb6, yb7, nfB, s2B, len2B,
                         vtx_enc, n_vtx, 2048, W, Bc,
                         w20, w21, w22, w23, w24, w25, w26, w27,
                         sNbrA, sNbrB, widxA, widxB, lane, v2A, v2B);
        else
            conv_pair<6>(ya0, ya1, ya2, ya3, ya4, ya5, ya6, ya7, nfA, s2A, len2A,
                         yb0, yb1, yb2, yb3, yb4, yb5, yb6, yb7, nfB, s2B, len2B,
                         vtx_enc, n_vtx, 2048, W, Bc,
                         w20, w21, w22, w23, w24, w25, w26, w27,
                         sNbrA, sNbrB, widxA, widxB, lane, v2A, v2B);
    }

    if (lane < 32) {
        feats2[(size_t)iA * 32 + lane] = v2A;
        feats2[(size_t)iB * 32 + lane] = v2B;
    }
}

// ---------------------------------------------------------------------------
// Kernel 3: output MLP 32 -> 64 -> 32 -> 4 -> 1 (lrelu each) + batch copy.
// ---------------------------------------------------------------------------
__launch_bounds__(256)
__global__ void out_mlp_kernel(const float* __restrict__ f2, const int* __restrict__ bpfc,
                               const float* __restrict__ w1, const float* __restrict__ b1,
                               const float* __restrict__ w2, const float* __restrict__ b2,
                               const float* __restrict__ w3, const float* __restrict__ b3,
                               const float* __restrict__ w4, const float* __restrict__ b4,
                               float* __restrict__ dout, int N) {
    __shared__ float sW1[32 * 64], sW2[64 * 32], sW3[32 * 4];
    __shared__ float sB1[64], sB2[32], sB3[4], sW4[4], sB4[1];
    __shared__ float ex1[4][64];
    __shared__ float ex2[4][32];

    const int t = threadIdx.x;
    for (int k = t; k < 2048; k += 256) { sW1[k] = w1[k]; sW2[k] = w2[k]; }
    if (t < 128) sW3[t] = w3[t];
    if (t < 64)  sB1[t] = b1[t];
    if (t < 32)  sB2[t] = b2[t];
    if (t < 4)   { sB3[t] = b3[t]; sW4[t] = w4[t]; }
    if (t == 0)  sB4[0] = b4[0];
    __syncthreads();

    const int w = t >> 6;
    const int lane = t & 63;
    const int i = blockIdx.x * 4 + w;

    const float* fr = f2 + (size_t)i * 32;

    float h1 = sB1[lane];
#pragma unroll
    for (int d = 0; d < 32; ++d) h1 = fmaf(fr[d], sW1[d * 64 + lane], h1);
    h1 = LRELU(h1);
    ex1[w][lane] = h1;
    __syncthreads();

    const int c = lane & 31;
    float h2 = sB2[c];
#pragma unroll
    for (int d = 0; d < 64; ++d) h2 = fmaf(ex1[w][d], sW2[d * 32 + c], h2);
    h2 = LRELU(h2);
    if (lane < 32) ex2[w][c] = h2;
    __syncthreads();

    float a0 = sB3[0], a1 = sB3[1], a2 = sB3[2], a3 = sB3[3];
#pragma unroll
    for (int d = 0; d < 32; ++d) {
        float e = ex2[w][d];
        a0 = fmaf(e, sW3[d * 4 + 0], a0);
        a1 = fmaf(e, sW3[d * 4 + 1], a1);
        a2 = fmaf(e, sW3[d * 4 + 2], a2);
        a3 = fmaf(e, sW3[d * 4 + 3], a3);
    }
    a0 = LRELU(a0); a1 = LRELU(a1); a2 = LRELU(a2); a3 = LRELU(a3);
    float o = sB4[0];
    o = fmaf(a0, sW4[0], o); o = fmaf(a1, sW4[1], o);
    o = fmaf(a2, sW4[2], o); o = fmaf(a3, sW4[3], o);
    o = LRELU(o);

    if (lane == 0) dout[i] = o;                       // output 0: (8192,1)
    if (lane == 1) dout[N + i] = (float)bpfc[i];      // output 1: batch_pfc
}

// ---------------------------------------------------------------------------
extern "C" void kernel_launch(void* const* d_in, const int* in_sizes, int n_in,
                              void* d_out, int out_size, void* d_ws, size_t ws_size,
                              hipStream_t stream) {
    const float* x_pfc     = (const float*)d_in[0];
    const float* x_vtx     = (const float*)d_in[1];
    const int*   batch_pfc = (const int*)d_in[2];
    const int*   batch_vtx = (const int*)d_in[3];
    const float* pfc_w1 = (const float*)d_in[4];
    const float* pfc_b1 = (const float*)d_in[5];
    const float* pfc_w2 = (const float*)d_in[6];
    const float* pfc_b2 = (const float*)d_in[7];
    const float* vtx_w1 = (const float*)d_in[8];
    const float* vtx_b1 = (const float*)d_in[9];
    const float* vtx_w2 = (const float*)d_in[10];
    const float* vtx_b2 = (const float*)d_in[11];
    const float* conv_w = (const float*)d_in[12];
    const float* conv_b = (const float*)d_in[13];
    const float* out_w1 = (const float*)d_in[14];
    const float* out_b1 = (const float*)d_in[15];
    const float* out_w2 = (const float*)d_in[16];
    const float* out_b2 = (const float*)d_in[17];
    const float* out_w3 = (const float*)d_in[18];
    const float* out_b3 = (const float*)d_in[19];
    const float* out_w4 = (const float*)d_in[20];
    const float* out_b4 = (const float*)d_in[21];

    const int N_PFC = 8192;

    float* ws = (float*)d_ws;
    float* pfc_enc = ws;                     // 8192*32
    float* vtx_enc = ws + 262144;            // 2048*32
    float* feats2  = ws + 327680;            // 8192*32
    float* n_pfc   = ws + 589824;            // 8192
    float* n_vtx   = ws + 598016;            // 2048
    int*   goff_pfc = (int*)(ws + 600064);   // 33
    int*   goff_vtx = (int*)(ws + 600128);   // 33

    encode_kernel<<<1280, 256, 0, stream>>>(x_pfc, x_vtx, batch_pfc, batch_vtx,
                                            pfc_w1, pfc_b1, pfc_w2, pfc_b2,
                                            vtx_w1, vtx_b1, vtx_w2, vtx_b2,
                                            pfc_enc, n_pfc, vtx_enc, n_vtx,
                                            goff_pfc, goff_vtx);

    fused_conv_kernel<<<2048, 128, 0, stream>>>(pfc_enc, n_pfc, vtx_enc, n_vtx,
                                                batch_pfc, goff_pfc, goff_vtx,
                                                conv_w, conv_b, feats2);

    out_mlp_kernel<<<2048, 256, 0, stream>>>(feats2, batch_pfc,
                                             out_w1, out_b1, out_w2, out_b2,
                                             out_w3, out_b3, out_w4, out_b4,
                                             (float*)d_out, N_PFC);
}